// Round 1
// baseline (4862.100 us; speedup 1.0000x reference)
//
#include <hip/hip_runtime.h>

// GraphSAGE 3-layer, fp32.
// Restructured via linearity: segment_sum(Wm @ concat(nf[src], ef)) ==
//   Wm_n @ segsum(nf[src]) + Wm_e @ segsum(ef) + deg * bm
// => scatter raw features (atomics), then 50k-row matvecs instead of 800k-row GEMM.

#define NN 50000
#define NE 800000
#define NIN 64
#define EDIM_ 64
#define HID_ 152
#define NOUT 64

// ---------------- degree ----------------
__global__ __launch_bounds__(256) void deg_kernel(const int* __restrict__ dst,
                                                  float* __restrict__ deg) {
    int e = blockIdx.x * 256 + threadIdx.x;
    if (e < NE) atomicAdd(&deg[dst[e]], 1.0f);
}

// ---------------- scatter edge feats: B[dst] += ef[e] ----------------
__global__ __launch_bounds__(256) void scatter_ef_kernel(const float* __restrict__ ef,
                                                         const int* __restrict__ dst,
                                                         float* __restrict__ B) {
    int gid = blockIdx.x * 256 + threadIdx.x;
    if (gid >= NE * EDIM_) return;
    int e = gid >> 6;       // EDIM_ == 64
    int j = gid & 63;
    atomicAdd(&B[dst[e] * EDIM_ + j], ef[gid]);
}

// ---------------- scatter node feats: A[dst] += nf[src] ----------------
template <int F>
__global__ __launch_bounds__(256) void scatter_nf_kernel(const float* __restrict__ nf,
                                                         const int* __restrict__ src,
                                                         const int* __restrict__ dst,
                                                         float* __restrict__ A) {
    int gid = blockIdx.x * 256 + threadIdx.x;
    if (gid >= NE * F) return;
    int e = gid / F;              // F is compile-time constant -> magic mul
    int j = gid - e * F;
    atomicAdd(&A[dst[e] * F + j], nf[src[e] * F + j]);
}

// ---------------- message combine: hn = (Wm_n@A + Wm_e@B + deg*bm) / max(deg,1) ----
template <int F_IN, int HM>
__global__ __launch_bounds__(256) void msg_kernel(const float* __restrict__ A,
                                                  const float* __restrict__ B,
                                                  const float* __restrict__ deg,
                                                  const float* __restrict__ Wm,
                                                  const float* __restrict__ bm,
                                                  float* __restrict__ hn) {
    int gid = blockIdx.x * 256 + threadIdx.x;
    if (gid >= NN * HM) return;
    int n = gid / HM;
    int o = gid - n * HM;
    const float* __restrict__ w = Wm + o * (F_IN + EDIM_);
    const float* __restrict__ a = A + n * F_IN;
    const float* __restrict__ b = B + n * EDIM_;
    float acc = 0.0f;
#pragma unroll 8
    for (int k = 0; k < F_IN; k++) acc += w[k] * a[k];
#pragma unroll 8
    for (int k = 0; k < EDIM_; k++) acc += w[F_IN + k] * b[k];
    float d = deg[n];
    float s = acc + d * bm[o];
    hn[gid] = s / fmaxf(d, 1.0f);
}

// ---------------- update: out = relu(Wa @ concat(nf, hn) + ba) ----------------
template <int F_IN, int HM, int HU>
__global__ __launch_bounds__(256) void upd_kernel(const float* __restrict__ nf,
                                                  const float* __restrict__ hn,
                                                  const float* __restrict__ Wa,
                                                  const float* __restrict__ ba,
                                                  float* __restrict__ out) {
    int gid = blockIdx.x * 256 + threadIdx.x;
    if (gid >= NN * HU) return;
    int n = gid / HU;
    int o = gid - n * HU;
    const float* __restrict__ w = Wa + o * (F_IN + HM);
    const float* __restrict__ x = nf + n * F_IN;
    const float* __restrict__ h = hn + n * HM;
    float acc = ba[o];
#pragma unroll 8
    for (int k = 0; k < F_IN; k++) acc += w[k] * x[k];
#pragma unroll 8
    for (int k = 0; k < HM; k++) acc += w[F_IN + k] * h[k];
    out[gid] = fmaxf(acc, 0.0f);
}

extern "C" void kernel_launch(void* const* d_in, const int* in_sizes, int n_in,
                              void* d_out, int out_size, void* d_ws, size_t ws_size,
                              hipStream_t stream) {
    const float* nfeats = (const float*)d_in[0];
    const float* efeats = (const float*)d_in[1];
    const float* Wm1 = (const float*)d_in[2];
    const float* bm1 = (const float*)d_in[3];
    const float* Wa1 = (const float*)d_in[4];
    const float* ba1 = (const float*)d_in[5];
    const float* Wm2 = (const float*)d_in[6];
    const float* bm2 = (const float*)d_in[7];
    const float* Wa2 = (const float*)d_in[8];
    const float* ba2 = (const float*)d_in[9];
    const float* Wm3 = (const float*)d_in[10];
    const float* bm3 = (const float*)d_in[11];
    const float* Wa3 = (const float*)d_in[12];
    const float* ba3 = (const float*)d_in[13];
    const int* src = (const int*)d_in[14];
    const int* dst = (const int*)d_in[15];
    float* out = (float*)d_out;

    float* ws = (float*)d_ws;
    // workspace layout (floats)
    float* deg = ws;                    // NN            (pad to 50048)
    float* B   = ws + 50048;            // NN*64  = 3,200,000
    float* A   = B + 3200000;           // NN*152 = 7,600,000 (max F_IN)
    float* hn  = A + 7600000;           // NN*152
    float* h1  = hn + 7600000;          // NN*152
    float* h2  = h1 + 7600000;          // NN*152
    // total = 33,650,048 floats ~= 134.6 MB

    const int BLK = 256;
    auto cdiv = [](long long a, long long b) { return (int)((a + b - 1) / b); };

    // zero deg + B (layer-invariant accumulators)
    hipMemsetAsync(deg, 0, (size_t)(50048 + 3200000) * 4, stream);
    deg_kernel<<<cdiv(NE, BLK), BLK, 0, stream>>>(dst, deg);
    scatter_ef_kernel<<<cdiv((long long)NE * EDIM_, BLK), BLK, 0, stream>>>(efeats, dst, B);

    // ---- layer 1 (F_IN=64) ----
    hipMemsetAsync(A, 0, (size_t)NN * NIN * 4, stream);
    scatter_nf_kernel<NIN><<<cdiv((long long)NE * NIN, BLK), BLK, 0, stream>>>(nfeats, src, dst, A);
    msg_kernel<NIN, HID_><<<cdiv((long long)NN * HID_, BLK), BLK, 0, stream>>>(A, B, deg, Wm1, bm1, hn);
    upd_kernel<NIN, HID_, HID_><<<cdiv((long long)NN * HID_, BLK), BLK, 0, stream>>>(nfeats, hn, Wa1, ba1, h1);

    // ---- layer 2 (F_IN=152) ----
    hipMemsetAsync(A, 0, (size_t)NN * HID_ * 4, stream);
    scatter_nf_kernel<HID_><<<cdiv((long long)NE * HID_, BLK), BLK, 0, stream>>>(h1, src, dst, A);
    msg_kernel<HID_, HID_><<<cdiv((long long)NN * HID_, BLK), BLK, 0, stream>>>(A, B, deg, Wm2, bm2, hn);
    upd_kernel<HID_, HID_, HID_><<<cdiv((long long)NN * HID_, BLK), BLK, 0, stream>>>(h1, hn, Wa2, ba2, h2);

    // ---- layer 3 (F_IN=152, out 64) ----
    hipMemsetAsync(A, 0, (size_t)NN * HID_ * 4, stream);
    scatter_nf_kernel<HID_><<<cdiv((long long)NE * HID_, BLK), BLK, 0, stream>>>(h2, src, dst, A);
    msg_kernel<HID_, NOUT><<<cdiv((long long)NN * NOUT, BLK), BLK, 0, stream>>>(A, B, deg, Wm3, bm3, hn);
    upd_kernel<HID_, NOUT, NOUT><<<cdiv((long long)NN * NOUT, BLK), BLK, 0, stream>>>(h2, hn, Wa3, ba3, out);
}

// Round 2
// 1918.760 us; speedup vs baseline: 2.5340x; 2.5340x over previous
//
#include <hip/hip_runtime.h>

// GraphSAGE 3-layer, fp32.
// Linearity restructuring: segment_sum(Wm @ concat(nf[src], ef)) ==
//   Wm_n @ segsum(nf[src]) + Wm_e @ segsum(ef) + deg * bm
// Round 1->2: matvec kernels (uncoalesced per-lane weight rows, VALUBusy 8%)
// replaced by LDS-tiled SGEMM (64x64 tile, BK=8, 4x4 microtile, fused epilogue).

#define NN 50000
#define NE 800000
#define NIN 64
#define EDIM_ 64
#define HID_ 152
#define NOUT 64

// ---------------- degree ----------------
__global__ __launch_bounds__(256) void deg_kernel(const int* __restrict__ dst,
                                                  float* __restrict__ deg) {
    int e = blockIdx.x * 256 + threadIdx.x;
    if (e < NE) atomicAdd(&deg[dst[e]], 1.0f);
}

// ---------------- scatter edge feats: B[dst] += ef[e] ----------------
__global__ __launch_bounds__(256) void scatter_ef_kernel(const float* __restrict__ ef,
                                                         const int* __restrict__ dst,
                                                         float* __restrict__ B) {
    int gid = blockIdx.x * 256 + threadIdx.x;
    if (gid >= NE * EDIM_) return;
    int e = gid >> 6;       // EDIM_ == 64
    int j = gid & 63;
    atomicAdd(&B[dst[e] * EDIM_ + j], ef[gid]);
}

// ---------------- scatter node feats: A[dst] += nf[src] ----------------
template <int F>
__global__ __launch_bounds__(256) void scatter_nf_kernel(const float* __restrict__ nf,
                                                         const int* __restrict__ src,
                                                         const int* __restrict__ dst,
                                                         float* __restrict__ A) {
    int gid = blockIdx.x * 256 + threadIdx.x;
    if (gid >= NE * F) return;
    int e = gid / F;              // compile-time const -> magic mul
    int j = gid - e * F;
    atomicAdd(&A[dst[e] * F + j], nf[src[e] * F + j]);
}

// ---------------- tiled SGEMM with fused epilogue ----------------
// out[M x NT] = X[M x (K1+K2)] @ W^T + epilogue, X = concat(X1[MxK1], X2[MxK2])
// MSG: v = (acc + deg*bias) / max(deg,1);  !MSG: v = relu(acc + bias)
// 64x64 block tile, BK=8 (divides 64 and 152 -> K segments never cross a tile),
// 256 threads, 4x4 microtile each.
template <int K1, int K2, int NT, bool MSG>
__global__ __launch_bounds__(256) void gemm_kernel(const float* __restrict__ X1,
                                                   const float* __restrict__ X2,
                                                   const float* __restrict__ W,
                                                   const float* __restrict__ bias,
                                                   const float* __restrict__ deg,
                                                   float* __restrict__ out) {
    constexpr int KT = K1 + K2;
    __shared__ float Xs[8][68];   // [k][m], pad to 68 for float4-aligned rows
    __shared__ float Ws[8][68];   // [k][o]
    const int t = threadIdx.x;
    const int m0 = blockIdx.x * 64;
    const int n0 = blockIdx.y * 64;
    const int lm = t >> 2;          // 0..63
    const int lk = (t & 3) * 2;     // 0,2,4,6
    const int tx = t & 15;          // col group
    const int ty = t >> 4;          // row group
    float acc[4][4] = {};

    const bool xrow_ok = (m0 + lm) < NN;
    const bool wrow_ok = (n0 + lm) < NT;

#pragma unroll
    for (int seg = 0; seg < 2; ++seg) {
        const float* __restrict__ X = seg ? X2 : X1;
        const int K = seg ? K2 : K1;
        const int koff = seg ? K1 : 0;
        for (int k0 = 0; k0 < K; k0 += 8) {
            float2 xv = make_float2(0.f, 0.f);
            if (xrow_ok) xv = *(const float2*)(X + (size_t)(m0 + lm) * K + k0 + lk);
            float2 wv = make_float2(0.f, 0.f);
            if (wrow_ok) wv = *(const float2*)(W + (size_t)(n0 + lm) * KT + koff + k0 + lk);
            __syncthreads();
            Xs[lk][lm] = xv.x; Xs[lk + 1][lm] = xv.y;
            Ws[lk][lm] = wv.x; Ws[lk + 1][lm] = wv.y;
            __syncthreads();
#pragma unroll
            for (int k = 0; k < 8; ++k) {
                float a0 = Xs[k][ty * 4 + 0], a1 = Xs[k][ty * 4 + 1];
                float a2 = Xs[k][ty * 4 + 2], a3 = Xs[k][ty * 4 + 3];
                float b0 = Ws[k][tx * 4 + 0], b1 = Ws[k][tx * 4 + 1];
                float b2 = Ws[k][tx * 4 + 2], b3 = Ws[k][tx * 4 + 3];
                acc[0][0] += a0 * b0; acc[0][1] += a0 * b1; acc[0][2] += a0 * b2; acc[0][3] += a0 * b3;
                acc[1][0] += a1 * b0; acc[1][1] += a1 * b1; acc[1][2] += a1 * b2; acc[1][3] += a1 * b3;
                acc[2][0] += a2 * b0; acc[2][1] += a2 * b1; acc[2][2] += a2 * b2; acc[2][3] += a2 * b3;
                acc[3][0] += a3 * b0; acc[3][1] += a3 * b1; acc[3][2] += a3 * b2; acc[3][3] += a3 * b3;
            }
        }
    }

    const int o0 = n0 + tx * 4;
    if (o0 >= NT) return;          // NT multiple of 4, o0 multiple of 4 -> whole float4 valid
    float b0 = bias[o0], b1 = bias[o0 + 1], b2 = bias[o0 + 2], b3 = bias[o0 + 3];
#pragma unroll
    for (int i = 0; i < 4; ++i) {
        int n = m0 + ty * 4 + i;
        if (n >= NN) break;
        float4 r;
        if (MSG) {
            float d = deg[n];
            float inv = 1.0f / fmaxf(d, 1.0f);
            r.x = (acc[i][0] + d * b0) * inv;
            r.y = (acc[i][1] + d * b1) * inv;
            r.z = (acc[i][2] + d * b2) * inv;
            r.w = (acc[i][3] + d * b3) * inv;
        } else {
            r.x = fmaxf(acc[i][0] + b0, 0.0f);
            r.y = fmaxf(acc[i][1] + b1, 0.0f);
            r.z = fmaxf(acc[i][2] + b2, 0.0f);
            r.w = fmaxf(acc[i][3] + b3, 0.0f);
        }
        *(float4*)(out + (size_t)n * NT + o0) = r;
    }
}

extern "C" void kernel_launch(void* const* d_in, const int* in_sizes, int n_in,
                              void* d_out, int out_size, void* d_ws, size_t ws_size,
                              hipStream_t stream) {
    const float* nfeats = (const float*)d_in[0];
    const float* efeats = (const float*)d_in[1];
    const float* Wm1 = (const float*)d_in[2];
    const float* bm1 = (const float*)d_in[3];
    const float* Wa1 = (const float*)d_in[4];
    const float* ba1 = (const float*)d_in[5];
    const float* Wm2 = (const float*)d_in[6];
    const float* bm2 = (const float*)d_in[7];
    const float* Wa2 = (const float*)d_in[8];
    const float* ba2 = (const float*)d_in[9];
    const float* Wm3 = (const float*)d_in[10];
    const float* bm3 = (const float*)d_in[11];
    const float* Wa3 = (const float*)d_in[12];
    const float* ba3 = (const float*)d_in[13];
    const int* src = (const int*)d_in[14];
    const int* dst = (const int*)d_in[15];
    float* out = (float*)d_out;

    float* ws = (float*)d_ws;
    float* deg = ws;                    // 50048
    float* B   = ws + 50048;            // NN*64
    float* A   = B + 3200000;           // NN*152 max
    float* hn  = A + 7600000;           // NN*152
    float* h1  = hn + 7600000;          // NN*152
    float* h2  = h1 + 7600000;          // NN*152

    const int BLK = 256;
    auto cdiv = [](long long a, long long b) { return (int)((a + b - 1) / b); };
    dim3 g152(cdiv(NN, 64), cdiv(152, 64));   // 782 x 3
    dim3 g64(cdiv(NN, 64), 1);                // 782 x 1

    hipMemsetAsync(deg, 0, (size_t)(50048 + 3200000) * 4, stream);
    deg_kernel<<<cdiv(NE, BLK), BLK, 0, stream>>>(dst, deg);
    scatter_ef_kernel<<<cdiv((long long)NE * EDIM_, BLK), BLK, 0, stream>>>(efeats, dst, B);

    // ---- layer 1 ----
    hipMemsetAsync(A, 0, (size_t)NN * NIN * 4, stream);
    scatter_nf_kernel<NIN><<<cdiv((long long)NE * NIN, BLK), BLK, 0, stream>>>(nfeats, src, dst, A);
    gemm_kernel<NIN, EDIM_, HID_, true><<<g152, BLK, 0, stream>>>(A, B, Wm1, bm1, deg, hn);
    gemm_kernel<NIN, HID_, HID_, false><<<g152, BLK, 0, stream>>>(nfeats, hn, Wa1, ba1, deg, h1);

    // ---- layer 2 ----
    hipMemsetAsync(A, 0, (size_t)NN * HID_ * 4, stream);
    scatter_nf_kernel<HID_><<<cdiv((long long)NE * HID_, BLK), BLK, 0, stream>>>(h1, src, dst, A);
    gemm_kernel<HID_, EDIM_, HID_, true><<<g152, BLK, 0, stream>>>(A, B, Wm2, bm2, deg, hn);
    gemm_kernel<HID_, HID_, HID_, false><<<g152, BLK, 0, stream>>>(h1, hn, Wa2, ba2, deg, h2);

    // ---- layer 3 ----
    hipMemsetAsync(A, 0, (size_t)NN * HID_ * 4, stream);
    scatter_nf_kernel<HID_><<<cdiv((long long)NE * HID_, BLK), BLK, 0, stream>>>(h2, src, dst, A);
    gemm_kernel<HID_, EDIM_, NOUT, true><<<g64, BLK, 0, stream>>>(A, B, Wm3, bm3, deg, hn);
    gemm_kernel<HID_, NOUT, NOUT, false><<<g64, BLK, 0, stream>>>(h2, hn, Wa3, ba3, deg, out);
}

// Round 3
// 912.473 us; speedup vs baseline: 5.3285x; 2.1028x over previous
//
#include <hip/hip_runtime.h>

// GraphSAGE 3-layer, fp32.
// Linearity: segsum(Wm@concat(nf[src],ef)) == Wm_n@segsum(nf[src]) + Wm_e@segsum(ef) + deg*bm
// Round 2->3: atomics wrote 486MB through to HBM per 152-scatter (L2 thrash).
// Replace with on-device CSR (hist + scan + cursor scatter), then atomic-free
// gather-sum aggregations (1 wave per node, float4 rows) reused 4x.

#define NN 50000
#define NE 800000
#define NIN 64
#define EDIM_ 64
#define HID_ 152
#define NOUT 64
#define PADN 50176   // 49 * 1024, scan-friendly padding of NN

// ---------------- histogram: integer in-degree ----------------
__global__ __launch_bounds__(256) void hist_kernel(const int* __restrict__ dst,
                                                   int* __restrict__ ideg) {
    int e = blockIdx.x * 256 + threadIdx.x;
    if (e < NE) atomicAdd(&ideg[dst[e]], 1);
}

// ---------------- exclusive scan, 3 kernels ----------------
// K1: each block scans 1024 elems (256 thr x 4), writes exclusive partial + block total
__global__ __launch_bounds__(256) void scan1_kernel(const int* __restrict__ in,
                                                    int* __restrict__ out,
                                                    int* __restrict__ bsum) {
    __shared__ int ws[4];
    int t = threadIdx.x;
    int base = blockIdx.x * 1024 + t * 4;
    int a0 = in[base], a1 = in[base + 1], a2 = in[base + 2], a3 = in[base + 3];
    int s = a0 + a1 + a2 + a3;
    int lane = t & 63, wid = t >> 6;
    int v = s;
#pragma unroll
    for (int d = 1; d < 64; d <<= 1) {
        int u = __shfl_up(v, d);
        if (lane >= d) v += u;
    }
    if (lane == 63) ws[wid] = v;
    __syncthreads();
    int wofs = 0;
    if (wid > 0) wofs += ws[0];
    if (wid > 1) wofs += ws[1];
    if (wid > 2) wofs += ws[2];
    int excl = wofs + v - s;
    out[base] = excl;
    out[base + 1] = excl + a0;
    out[base + 2] = excl + a0 + a1;
    out[base + 3] = excl + a0 + a1 + a2;
    if (t == 255) bsum[blockIdx.x] = wofs + v;
}

// K2: single wave exclusive-scans the <=64 block totals in place
__global__ __launch_bounds__(64) void scan2_kernel(int* __restrict__ bsum, int nb) {
    int t = threadIdx.x;
    int orig = (t < nb) ? bsum[t] : 0;
    int v = orig;
#pragma unroll
    for (int d = 1; d < 64; d <<= 1) {
        int u = __shfl_up(v, d);
        if (t >= d) v += u;
    }
    if (t < nb) bsum[t] = v - orig;
}

// K3: add block offsets
__global__ __launch_bounds__(256) void scan3_kernel(int* __restrict__ out,
                                                    const int* __restrict__ bsum) {
    int base = blockIdx.x * 1024 + threadIdx.x * 4;
    int b = bsum[blockIdx.x];
    out[base] += b; out[base + 1] += b; out[base + 2] += b; out[base + 3] += b;
}

// ---------------- scatter edges into CSR order ----------------
__global__ __launch_bounds__(256) void scatter_edges_kernel(const int* __restrict__ src,
                                                            const int* __restrict__ dst,
                                                            int* __restrict__ cursor,
                                                            int* __restrict__ csr_nf,
                                                            int* __restrict__ csr_ef) {
    int e = blockIdx.x * 256 + threadIdx.x;
    if (e >= NE) return;
    int d = dst[e];
    int pos = atomicAdd(&cursor[d], 1);
    csr_nf[pos] = src[e];
    csr_ef[pos] = e;
}

// ---------------- gather-sum aggregation ----------------
// out[n][0:F] = sum over CSR segment of table[rows[i]][0:F]
// 256 thr = 4 waves; each wave handles NPW nodes (NPW = 64/(F/4)).
template <int F>
__global__ __launch_bounds__(256) void agg_kernel(const float* __restrict__ table,
                                                  const int* __restrict__ rows,
                                                  const int* __restrict__ off,
                                                  float* __restrict__ out) {
    constexpr int C = F / 4;          // float4 chunks per row
    constexpr int NPW = 64 / C;       // nodes per wave (4 for F=64, 1 for F=152)
    int t = threadIdx.x;
    int lane = t & 63, wid = t >> 6;
    int sub = lane / C;
    int ch = lane - sub * C;
    int n = (blockIdx.x * 4 + wid) * NPW + sub;
    if (sub >= NPW || n >= NN) return;
    int s = off[n], e = off[n + 1];
    float ax0 = 0.f, ax1 = 0.f, ax2 = 0.f, ax3 = 0.f;
    float bx0 = 0.f, bx1 = 0.f, bx2 = 0.f, bx3 = 0.f;
    int i = s;
    for (; i + 1 < e; i += 2) {
        int r0 = rows[i], r1 = rows[i + 1];
        float4 v0 = *(const float4*)(table + (size_t)r0 * F + ch * 4);
        float4 v1 = *(const float4*)(table + (size_t)r1 * F + ch * 4);
        ax0 += v0.x; ax1 += v0.y; ax2 += v0.z; ax3 += v0.w;
        bx0 += v1.x; bx1 += v1.y; bx2 += v1.z; bx3 += v1.w;
    }
    if (i < e) {
        int r0 = rows[i];
        float4 v0 = *(const float4*)(table + (size_t)r0 * F + ch * 4);
        ax0 += v0.x; ax1 += v0.y; ax2 += v0.z; ax3 += v0.w;
    }
    float4 r;
    r.x = ax0 + bx0; r.y = ax1 + bx1; r.z = ax2 + bx2; r.w = ax3 + bx3;
    *(float4*)(out + (size_t)n * F + ch * 4) = r;
}

// ---------------- tiled SGEMM with fused epilogue ----------------
// out[M x NT] = concat(X1[MxK1], X2[MxK2]) @ W^T + epilogue
// MSG: (acc + deg*bias)/max(deg,1), deg = off[n+1]-off[n];  !MSG: relu(acc + bias)
template <int K1, int K2, int NT, bool MSG>
__global__ __launch_bounds__(256) void gemm_kernel(const float* __restrict__ X1,
                                                   const float* __restrict__ X2,
                                                   const float* __restrict__ W,
                                                   const float* __restrict__ bias,
                                                   const int* __restrict__ off,
                                                   float* __restrict__ out) {
    constexpr int KT = K1 + K2;
    __shared__ float Xs[8][68];
    __shared__ float Ws[8][68];
    const int t = threadIdx.x;
    const int m0 = blockIdx.x * 64;
    const int n0 = blockIdx.y * 64;
    const int lm = t >> 2;
    const int lk = (t & 3) * 2;
    const int tx = t & 15;
    const int ty = t >> 4;
    float acc[4][4] = {};

    const bool xrow_ok = (m0 + lm) < NN;
    const bool wrow_ok = (n0 + lm) < NT;

#pragma unroll
    for (int seg = 0; seg < 2; ++seg) {
        const float* __restrict__ X = seg ? X2 : X1;
        const int K = seg ? K2 : K1;
        const int koff = seg ? K1 : 0;
        for (int k0 = 0; k0 < K; k0 += 8) {
            float2 xv = make_float2(0.f, 0.f);
            if (xrow_ok) xv = *(const float2*)(X + (size_t)(m0 + lm) * K + k0 + lk);
            float2 wv = make_float2(0.f, 0.f);
            if (wrow_ok) wv = *(const float2*)(W + (size_t)(n0 + lm) * KT + koff + k0 + lk);
            __syncthreads();
            Xs[lk][lm] = xv.x; Xs[lk + 1][lm] = xv.y;
            Ws[lk][lm] = wv.x; Ws[lk + 1][lm] = wv.y;
            __syncthreads();
#pragma unroll
            for (int k = 0; k < 8; ++k) {
                float a0 = Xs[k][ty * 4 + 0], a1 = Xs[k][ty * 4 + 1];
                float a2 = Xs[k][ty * 4 + 2], a3 = Xs[k][ty * 4 + 3];
                float b0 = Ws[k][tx * 4 + 0], b1 = Ws[k][tx * 4 + 1];
                float b2 = Ws[k][tx * 4 + 2], b3 = Ws[k][tx * 4 + 3];
                acc[0][0] += a0 * b0; acc[0][1] += a0 * b1; acc[0][2] += a0 * b2; acc[0][3] += a0 * b3;
                acc[1][0] += a1 * b0; acc[1][1] += a1 * b1; acc[1][2] += a1 * b2; acc[1][3] += a1 * b3;
                acc[2][0] += a2 * b0; acc[2][1] += a2 * b1; acc[2][2] += a2 * b2; acc[2][3] += a2 * b3;
                acc[3][0] += a3 * b0; acc[3][1] += a3 * b1; acc[3][2] += a3 * b2; acc[3][3] += a3 * b3;
            }
        }
    }

    const int o0 = n0 + tx * 4;
    if (o0 >= NT) return;
    float b0 = bias[o0], b1 = bias[o0 + 1], b2 = bias[o0 + 2], b3 = bias[o0 + 3];
#pragma unroll
    for (int i = 0; i < 4; ++i) {
        int n = m0 + ty * 4 + i;
        if (n >= NN) break;
        float4 r;
        if (MSG) {
            float d = (float)(off[n + 1] - off[n]);
            float inv = 1.0f / fmaxf(d, 1.0f);
            r.x = (acc[i][0] + d * b0) * inv;
            r.y = (acc[i][1] + d * b1) * inv;
            r.z = (acc[i][2] + d * b2) * inv;
            r.w = (acc[i][3] + d * b3) * inv;
        } else {
            r.x = fmaxf(acc[i][0] + b0, 0.0f);
            r.y = fmaxf(acc[i][1] + b1, 0.0f);
            r.z = fmaxf(acc[i][2] + b2, 0.0f);
            r.w = fmaxf(acc[i][3] + b3, 0.0f);
        }
        *(float4*)(out + (size_t)n * NT + o0) = r;
    }
}

extern "C" void kernel_launch(void* const* d_in, const int* in_sizes, int n_in,
                              void* d_out, int out_size, void* d_ws, size_t ws_size,
                              hipStream_t stream) {
    const float* nfeats = (const float*)d_in[0];
    const float* efeats = (const float*)d_in[1];
    const float* Wm1 = (const float*)d_in[2];
    const float* bm1 = (const float*)d_in[3];
    const float* Wa1 = (const float*)d_in[4];
    const float* ba1 = (const float*)d_in[5];
    const float* Wm2 = (const float*)d_in[6];
    const float* bm2 = (const float*)d_in[7];
    const float* Wa2 = (const float*)d_in[8];
    const float* ba2 = (const float*)d_in[9];
    const float* Wm3 = (const float*)d_in[10];
    const float* bm3 = (const float*)d_in[11];
    const float* Wa3 = (const float*)d_in[12];
    const float* ba3 = (const float*)d_in[13];
    const int* src = (const int*)d_in[14];
    const int* dst = (const int*)d_in[15];
    float* out = (float*)d_out;

    // workspace layout (4-byte units)
    int* iws = (int*)d_ws;
    int* ideg   = iws;                  // PADN
    int* off    = iws + PADN;           // PADN
    int* cursor = iws + 2 * PADN;       // PADN
    int* csr_nf = iws + 3 * PADN;       // NE
    int* csr_ef = csr_nf + NE;          // NE
    float* B = (float*)(csr_ef + NE);   // NN*64  = 3,200,000
    float* P = B + 3200000;             // NN*152 = 7,600,000
    float* Q = P + 7600000;             // NN*152
    float* R = Q + 7600000;             // NN*152
    // total = 3*50176 + 2*800000 + 3200000 + 3*7600000 = 27,750,528 * 4B ~= 111 MB

    const int BLK = 256;
    auto cdiv = [](long long a, long long b) { return (int)((a + b - 1) / b); };
    dim3 g152(cdiv(NN, 64), cdiv(152, 64));
    dim3 g64(cdiv(NN, 64), 1);
    const int NB = PADN / 1024;  // 49

    // ---- CSR build ----
    hipMemsetAsync(ideg, 0, (size_t)PADN * 4, stream);
    hist_kernel<<<cdiv(NE, BLK), BLK, 0, stream>>>(dst, ideg);
    scan1_kernel<<<NB, 256, 0, stream>>>(ideg, off, cursor);  // cursor[0..NB) = block sums (temp)
    scan2_kernel<<<1, 64, 0, stream>>>(cursor, NB);
    scan3_kernel<<<NB, 256, 0, stream>>>(off, cursor);
    hipMemcpyAsync(cursor, off, (size_t)NN * 4, hipMemcpyDeviceToDevice, stream);
    scatter_edges_kernel<<<cdiv(NE, BLK), BLK, 0, stream>>>(src, dst, cursor, csr_nf, csr_ef);

    // ---- layer-invariant: B = segsum(ef) ----
    agg_kernel<EDIM_><<<cdiv(NN, 16), BLK, 0, stream>>>(efeats, csr_ef, off, B);

    // ---- layer 1 ----
    agg_kernel<NIN><<<cdiv(NN, 16), BLK, 0, stream>>>(nfeats, csr_nf, off, P);
    gemm_kernel<NIN, EDIM_, HID_, true><<<g152, BLK, 0, stream>>>(P, B, Wm1, bm1, off, Q);
    gemm_kernel<NIN, HID_, HID_, false><<<g152, BLK, 0, stream>>>(nfeats, Q, Wa1, ba1, off, R);  // h1 = R

    // ---- layer 2 ----
    agg_kernel<HID_><<<cdiv(NN, 4), BLK, 0, stream>>>(R, csr_nf, off, P);
    gemm_kernel<HID_, EDIM_, HID_, true><<<g152, BLK, 0, stream>>>(P, B, Wm2, bm2, off, Q);
    gemm_kernel<HID_, HID_, HID_, false><<<g152, BLK, 0, stream>>>(R, Q, Wa2, ba2, off, P);      // h2 = P

    // ---- layer 3 ----
    agg_kernel<HID_><<<cdiv(NN, 4), BLK, 0, stream>>>(P, csr_nf, off, Q);
    gemm_kernel<HID_, EDIM_, NOUT, true><<<g64, BLK, 0, stream>>>(Q, B, Wm3, bm3, off, R);       // hn3 = R
    gemm_kernel<HID_, NOUT, NOUT, false><<<g64, BLK, 0, stream>>>(P, R, Wa3, ba3, off, out);
}